// Round 5
// baseline (264.334 us; speedup 1.0000x reference)
//
#include <hip/hip_runtime.h>
#include <hip/hip_bf16.h>

#define H_ 64
#define FF_ 128
#define V_ 64
#define B_ 256
#define L_ 4096

__device__ __forceinline__ float wsum64(float x) {
  #pragma unroll
  for (int m = 32; m; m >>= 1) x += __shfl_xor(x, m, 64);
  return x;
}
__device__ __forceinline__ float readlane_f(float x, int lane) {
  return __int_as_float(__builtin_amdgcn_readlane(__float_as_int(x), lane));
}

// ---------------------------------------------------------------------------
// build_all: 1 block x 1024 threads (16 waves). Each wave computes 4 tokens'
// MLP+LN+projections independently (wave-local LDS slices, no barriers), then
// one barrier and a cooperative 64x64 Gram build.
// ---------------------------------------------------------------------------
__global__ __launch_bounds__(1024) void build_all(
    const float* __restrict__ embed, const float* __restrict__ W1,
    const float* __restrict__ b1, const float* __restrict__ W2,
    const float* __restrict__ b2, const float* __restrict__ gamma,
    const float* __restrict__ beta, const float* __restrict__ Wk,
    const float* __restrict__ Wv, const float* __restrict__ Wq,
    float2* __restrict__ kv_table, float* __restrict__ q_table,
    float* __restrict__ gram)
{
  const int tid = threadIdx.x;
  const int w = tid >> 6, l = tid & 63;
  __shared__ float sh_h[16][64];
  __shared__ float sh_a[16][128];
  __shared__ float sh_n[16][64];
  __shared__ float kn_all[64][65];   // padded: avoids 32-way conflict in Gram phase

  for (int tok = w; tok < 64; tok += 16) {
    float h = embed[tok * 64 + l];
    sh_h[w][l] = h;
    float a0 = b1[l], a1 = b1[l + 64];
    #pragma unroll 8
    for (int j = 0; j < 64; ++j) {
      float hj = sh_h[w][j];
      a0 = fmaf(hj, W1[j * 128 + l], a0);
      a1 = fmaf(hj, W1[j * 128 + l + 64], a1);
    }
    sh_a[w][l] = fmaxf(a0, 0.f);
    sh_a[w][l + 64] = fmaxf(a1, 0.f);
    float x = h + b2[l];
    #pragma unroll 8
    for (int f = 0; f < 128; ++f) x = fmaf(sh_a[w][f], W2[f * 64 + l], x);
    float mu = wsum64(x) * (1.f / 64.f);
    float d = x - mu;
    float var = wsum64(d * d) * (1.f / 64.f);
    float hn = d * rsqrtf(var + 1e-5f) * gamma[l] + beta[l];
    sh_n[w][l] = hn;
    float k = 0.f, v = 0.f, q = 0.f;
    #pragma unroll 8
    for (int i = 0; i < 64; ++i) {
      float hi = sh_n[w][i];
      k = fmaf(hi, Wk[i * 64 + l], k);
      v = fmaf(hi, Wv[i * 64 + l], v);
      q = fmaf(hi, Wq[i * 64 + l], q);
    }
    float n2 = wsum64(k * k);
    float kn = k / fmaxf(sqrtf(n2), 1e-12f);
    kv_table[tok * 64 + l] = make_float2(kn, v);
    q_table[tok * 64 + l] = q;
    kn_all[tok][l] = kn;
  }
  __syncthreads();
  for (int e = tid; e < 4096; e += 1024) {
    int row = e >> 6, col = e & 63;
    float s = 0.f;
    #pragma unroll 8
    for (int i = 0; i < 64; ++i)
      s = fmaf(kn_all[row][i], kn_all[col][i], s);
    gram[e] = s;
  }
}

// ---------------------------------------------------------------------------
// scan_kernel: per-batch backward vector scan in Gram-space, serial form with
// a depth-3 (rows) / depth-4 (tokens) rotating software pipeline.
//   per step t: c = a[s_t]; a -= c*Gram[s_t][:]; r += c*V[s_t][:]
// Gram and V rows fused in one float2 LDS table (1 ds_read_b64 per step).
// Steps: 3 singles (t=4094..4092) + 1023 chunks of 4 (t=4091..0).
// ---------------------------------------------------------------------------
struct RowBuf { float2 r0, r1, r2, r3; int s0, s1, s2, s3; };

__device__ __forceinline__ void prep_rows(int4 tv, RowBuf& rb,
                                          const float2* __restrict__ gvl) {
  rb.s0 = __builtin_amdgcn_readfirstlane(tv.w);   // step t   (first)
  rb.s1 = __builtin_amdgcn_readfirstlane(tv.z);   // step t-1
  rb.s2 = __builtin_amdgcn_readfirstlane(tv.y);   // step t-2
  rb.s3 = __builtin_amdgcn_readfirstlane(tv.x);   // step t-3
  rb.r0 = gvl[rb.s0 * 64];
  rb.r1 = gvl[rb.s1 * 64];
  rb.r2 = gvl[rb.s2 * 64];
  rb.r3 = gvl[rb.s3 * 64];
}
__device__ __forceinline__ void exec4(const RowBuf& rb, float& a, float& r) {
  float d;
  d = readlane_f(a, rb.s0); a = fmaf(-d, rb.r0.x, a); r = fmaf(d, rb.r0.y, r);
  d = readlane_f(a, rb.s1); a = fmaf(-d, rb.r1.x, a); r = fmaf(d, rb.r1.y, r);
  d = readlane_f(a, rb.s2); a = fmaf(-d, rb.r2.x, a); r = fmaf(d, rb.r2.y, r);
  d = readlane_f(a, rb.s3); a = fmaf(-d, rb.r3.x, a); r = fmaf(d, rb.r3.y, r);
}

__global__ __launch_bounds__(64) void scan_kernel(
    const int* __restrict__ seq, const float2* __restrict__ kv_table,
    const float* __restrict__ q_table, const float* __restrict__ gram,
    const float* __restrict__ Wr, const float* __restrict__ br,
    const float* __restrict__ Wo, const float* __restrict__ bo,
    float* __restrict__ out)
{
  const int b = blockIdx.x, l = threadIdx.x;
  __shared__ __align__(16) int stok[L_];   // 16 KB
  __shared__ float kn_s[64 * 65];          // padded kn rows (a-init)
  __shared__ float2 gv_s[64 * 64];         // (gram, v) fused rows, 32 KB
  __shared__ float qs[64], sh_r[64], sh_rr[64];

  { // stage sequence (int4)
    const int4* src = reinterpret_cast<const int4*>(seq + b * L_);
    int4* dst = reinterpret_cast<int4*>(stok);
    for (int i = l; i < 1024; i += 64) dst[i] = src[i];
  }
  // stage tables: kn (padded) + fused (gram, v)
  for (int idx = l * 2; idx < 4096; idx += 128) {
    float4 kv2 = *reinterpret_cast<const float4*>(&kv_table[idx]); // 2 float2
    float2 g2 = *reinterpret_cast<const float2*>(&gram[idx]);
    int row = idx >> 6, col = idx & 63;
    kn_s[row * 65 + col] = kv2.x;
    kn_s[row * 65 + col + 1] = kv2.z;
    gv_s[idx] = make_float2(g2.x, kv2.y);
    gv_s[idx + 1] = make_float2(g2.y, kv2.w);
  }
  __syncthreads();

  const int tq = stok[L_ - 1];
  qs[l] = q_table[tq * 64 + l];
  __syncthreads();

  // a_l = kn_vocab[l] . q
  float a = 0.f;
  #pragma unroll 8
  for (int i = 0; i < 64; ++i) a = fmaf(kn_s[l * 65 + i], qs[i], a);
  float r = 0.f;

  const float2* gvl = gv_s + l;

  // pipeline prologue: TOK(c) lives at stok[4088-4c]
  int4 tk0 = *reinterpret_cast<const int4*>(&stok[4088]);  // TOK(0)
  int4 tk1 = *reinterpret_cast<const int4*>(&stok[4084]);  // TOK(1)
  int4 tk2 = *reinterpret_cast<const int4*>(&stok[4080]);  // TOK(2)
  int4 tk3 = *reinterpret_cast<const int4*>(&stok[4076]);  // TOK(3)
  RowBuf rb0, rb1, rb2, rb3;
  prep_rows(tk0, rb0, gvl);                                // rows chunk 0
  prep_rows(tk1, rb1, gvl);                                // rows chunk 1
  prep_rows(tk2, rb2, gvl);                                // rows chunk 2
  tk0 = *reinterpret_cast<const int4*>(&stok[4072]);       // TOK(4)
  tk1 = *reinterpret_cast<const int4*>(&stok[4068]);       // TOK(5)
  tk2 = *reinterpret_cast<const int4*>(&stok[4064]);       // TOK(6)

  // 3 singles: t = 4094, 4093, 4092
  #pragma unroll
  for (int t = 4094; t >= 4092; --t) {
    int s0 = __builtin_amdgcn_readfirstlane(stok[t]);
    float2 g = gvl[s0 * 64];
    float c0 = readlane_f(a, s0);
    a = fmaf(-c0, g.x, a);
    r = fmaf(c0, g.y, r);
  }

  // main loop: 255 iterations x 4 chunks; chunk c covers t = 4091-4c .. 4088-4c
  for (int c = 0; c < 1020; c += 4) {
    const int base = 4088 - 4 * c;
    // phase 0: chunk c
    prep_rows(tk3, rb3, gvl);                                     // PREP(c+3)
    { int idx = base - 28; if (idx < 0) idx = 0;                  // TOK(c+7)
      tk3 = *reinterpret_cast<const int4*>(&stok[idx]); }
    exec4(rb0, a, r);                                             // EXEC(c)
    // phase 1: chunk c+1
    prep_rows(tk0, rb0, gvl);                                     // PREP(c+4)
    { int idx = base - 32; if (idx < 0) idx = 0;                  // TOK(c+8)
      tk0 = *reinterpret_cast<const int4*>(&stok[idx]); }
    exec4(rb1, a, r);
    // phase 2: chunk c+2
    prep_rows(tk1, rb1, gvl);                                     // PREP(c+5)
    { int idx = base - 36; if (idx < 0) idx = 0;                  // TOK(c+9)
      tk1 = *reinterpret_cast<const int4*>(&stok[idx]); }
    exec4(rb2, a, r);
    // phase 3: chunk c+3
    prep_rows(tk2, rb2, gvl);                                     // PREP(c+6)
    { int idx = base - 40; if (idx < 0) idx = 0;                  // TOK(c+10)
      tk2 = *reinterpret_cast<const int4*>(&stok[idx]); }
    exec4(rb3, a, r);
  }
  // epilogue: chunks 1020..1022 (prepped in-loop)
  exec4(rb0, a, r);
  exec4(rb1, a, r);
  exec4(rb2, a, r);

  // tail: out = (r @ Wr + br) @ Wo + bo
  sh_r[l] = r;
  __syncthreads();
  float rr = br[l];
  #pragma unroll 8
  for (int i = 0; i < 64; ++i) rr = fmaf(sh_r[i], Wr[i * 64 + l], rr);
  sh_rr[l] = rr;
  __syncthreads();
  float o = bo[l];
  #pragma unroll 8
  for (int j = 0; j < 64; ++j) o = fmaf(sh_rr[j], Wo[j * 64 + l], o);
  out[b * V_ + l] = o;
}

extern "C" void kernel_launch(void* const* d_in, const int* in_sizes, int n_in,
                              void* d_out, int out_size, void* d_ws, size_t ws_size,
                              hipStream_t stream) {
  const int*   seq   = (const int*)  d_in[0];
  const float* embed = (const float*)d_in[1];
  const float* W1    = (const float*)d_in[2];
  const float* b1    = (const float*)d_in[3];
  const float* W2    = (const float*)d_in[4];
  const float* b2    = (const float*)d_in[5];
  const float* gamma = (const float*)d_in[6];
  const float* beta  = (const float*)d_in[7];
  const float* Wk    = (const float*)d_in[8];
  const float* Wv    = (const float*)d_in[9];
  const float* Wq    = (const float*)d_in[10];
  const float* Wr    = (const float*)d_in[11];
  const float* br    = (const float*)d_in[12];
  const float* Wo    = (const float*)d_in[13];
  const float* bo    = (const float*)d_in[14];
  float* out = (float*)d_out;

  float2* kv_table = (float2*)d_ws;                     // 32 KB
  float*  q_table  = (float*)((char*)d_ws + 32 * 1024); // 16 KB
  float*  gram     = (float*)((char*)d_ws + 48 * 1024); // 16 KB

  build_all<<<1, 1024, 0, stream>>>(embed, W1, b1, W2, b2, gamma, beta,
                                    Wk, Wv, Wq, kv_table, q_table, gram);
  scan_kernel<<<B_, 64, 0, stream>>>(seq, kv_table, q_table, gram,
                                     Wr, br, Wo, bo, out);
}

// Round 9
// 204.715 us; speedup vs baseline: 1.2912x; 1.2912x over previous
//
#include <hip/hip_runtime.h>
#include <hip/hip_bf16.h>

#define H_ 64
#define FF_ 128
#define V_ 64
#define B_ 256
#define L_ 4096

typedef __attribute__((ext_vector_type(2))) float f32x2;
typedef __attribute__((ext_vector_type(4))) int i32x4;

__device__ __forceinline__ float wsum64(float x) {
  #pragma unroll
  for (int m = 32; m; m >>= 1) x += __shfl_xor(x, m, 64);
  return x;
}
__device__ __forceinline__ float readlane_f(float x, int lane) {
  return __int_as_float(__builtin_amdgcn_readlane(__float_as_int(x), lane));
}

// ---------------------------------------------------------------------------
// Kernel 1: per-token-id tables (64 blocks x 64 threads; verified round 3)
// ---------------------------------------------------------------------------
__global__ __launch_bounds__(64) void build_tables(
    const float* __restrict__ embed, const float* __restrict__ W1,
    const float* __restrict__ b1, const float* __restrict__ W2,
    const float* __restrict__ b2, const float* __restrict__ gamma,
    const float* __restrict__ beta, const float* __restrict__ Wk,
    const float* __restrict__ Wv, const float* __restrict__ Wq,
    float2* __restrict__ kv_table, float* __restrict__ q_table)
{
  const int tok = blockIdx.x;
  const int l = threadIdx.x;
  __shared__ float sh_h[H_];
  __shared__ float sh_a[FF_];
  __shared__ float sh_n[H_];

  float h = embed[tok * H_ + l];
  sh_h[l] = h;
  __syncthreads();

  float a0 = b1[l], a1 = b1[l + 64];
  #pragma unroll 8
  for (int j = 0; j < H_; ++j) {
    float hj = sh_h[j];
    a0 = fmaf(hj, W1[j * FF_ + l], a0);
    a1 = fmaf(hj, W1[j * FF_ + l + 64], a1);
  }
  sh_a[l]      = fmaxf(a0, 0.f);
  sh_a[l + 64] = fmaxf(a1, 0.f);
  __syncthreads();

  float x = h + b2[l];
  #pragma unroll 8
  for (int f = 0; f < FF_; ++f) x = fmaf(sh_a[f], W2[f * H_ + l], x);

  float mu = wsum64(x) * (1.0f / 64.0f);
  float d = x - mu;
  float var = wsum64(d * d) * (1.0f / 64.0f);
  float hn = d * rsqrtf(var + 1e-5f) * gamma[l] + beta[l];
  sh_n[l] = hn;
  __syncthreads();

  float k = 0.f, v = 0.f, q = 0.f;
  #pragma unroll 8
  for (int i = 0; i < H_; ++i) {
    float hi = sh_n[i];
    k = fmaf(hi, Wk[i * H_ + l], k);
    v = fmaf(hi, Wv[i * H_ + l], v);
    q = fmaf(hi, Wq[i * H_ + l], q);
  }
  float n2 = wsum64(k * k);
  float kn = k / fmaxf(sqrtf(n2), 1e-12f);
  kv_table[tok * H_ + l] = make_float2(kn, v);
  q_table[tok * H_ + l] = q;
}

// ---------------------------------------------------------------------------
// Kernel 2: Gram[a][j] = kn_a . kn_j
// ---------------------------------------------------------------------------
__global__ __launch_bounds__(64) void build_gram(
    const float2* __restrict__ kv_table, float* __restrict__ gram)
{
  const int arow = blockIdx.x;
  const int j = threadIdx.x;
  float s = 0.f;
  #pragma unroll 8
  for (int i = 0; i < H_; ++i)
    s = fmaf(kv_table[arow * H_ + i].x, kv_table[j * H_ + i].x, s);
  gram[arow * H_ + j] = s;
}

// ---------------------------------------------------------------------------
// Kernel 3: serial backward vector scan in Gram-space with an inline-asm
// software pipeline (counted lgkmcnt waits; compiler can't defeat it).
//   per step: c = a[s_t]; a -= c*Gram[s_t][:]; r += c*V[s_t][:]
// Phase p (p = 0..1022, chunk p = 4 steps): issue rows for chunk p+2 (4x
// ds_read_b64) + token quad for chunk p+4 (1x ds_read_b128); wait
// lgkmcnt(5) before consuming tokens/rows loaded 2 phases ago.
// Steady-state queue at phase p start: [P(p):4, T(p+2):1, P(p+1):4, T(p+3):1]
// = 10; LGKM(5) drains exactly P(p)+T(p+2) (in-order completion).
// NOTE: pasted register names are parenthesized — (rb##S##0).x — because
// "0.x"/"0.y" otherwise lex as single pp-number tokens and break ##.
// ---------------------------------------------------------------------------
#define DS64(dst, addr)  asm volatile("ds_read_b64 %0, %1"  : "=v"(dst) : "v"(addr))
#define DS128(dst, addr) asm volatile("ds_read_b128 %0, %1" : "=v"(dst) : "v"(addr))
#define LGKM(n) do { asm volatile("s_waitcnt lgkmcnt(" #n ")" ::: "memory"); \
                     __builtin_amdgcn_sched_barrier(0); } while (0)

#define PREP(S) do { \
  ss##S##0 = __builtin_amdgcn_readfirstlane(tk##S.w); \
  ss##S##1 = __builtin_amdgcn_readfirstlane(tk##S.z); \
  ss##S##2 = __builtin_amdgcn_readfirstlane(tk##S.y); \
  ss##S##3 = __builtin_amdgcn_readfirstlane(tk##S.x); \
  DS64(rb##S##0, gv_base + (unsigned)(ss##S##0) * 512u); \
  DS64(rb##S##1, gv_base + (unsigned)(ss##S##1) * 512u); \
  DS64(rb##S##2, gv_base + (unsigned)(ss##S##2) * 512u); \
  DS64(rb##S##3, gv_base + (unsigned)(ss##S##3) * 512u); \
} while (0)

#define TOKLD(S) do { \
  DS128(tk##S, atok); \
  atok = (atok >= tok_base + 16u) ? (atok - 16u) : tok_base; \
} while (0)

#define EXEC(S) do { \
  float d_; \
  d_ = readlane_f(a, ss##S##0); a = fmaf(-d_, (rb##S##0).x, a); r = fmaf(d_, (rb##S##0).y, r); \
  d_ = readlane_f(a, ss##S##1); a = fmaf(-d_, (rb##S##1).x, a); r = fmaf(d_, (rb##S##1).y, r); \
  d_ = readlane_f(a, ss##S##2); a = fmaf(-d_, (rb##S##2).x, a); r = fmaf(d_, (rb##S##2).y, r); \
  d_ = readlane_f(a, ss##S##3); a = fmaf(-d_, (rb##S##3).x, a); r = fmaf(d_, (rb##S##3).y, r); \
} while (0)

#define PHASE(EP, PP) do { \
  LGKM(5); \
  PREP(PP); \
  TOKLD(EP); \
  LGKM(11); \
  EXEC(EP); \
} while (0)

__global__ __launch_bounds__(64) void scan_kernel(
    const int* __restrict__ seq, const float2* __restrict__ kv_table,
    const float* __restrict__ q_table, const float* __restrict__ gram,
    const float* __restrict__ Wr, const float* __restrict__ br,
    const float* __restrict__ Wo, const float* __restrict__ bo,
    float* __restrict__ out)
{
  const int b = blockIdx.x, l = threadIdx.x;
  __shared__ __align__(16) int stok[L_];   // 16 KB
  __shared__ float kn_s[64 * 65];          // padded kn rows (a-init)
  __shared__ __align__(8) float2 gv_s[64 * 64]; // (gram, v) fused rows, 32 KB
  __shared__ float qs[64], sh_r[64], sh_rr[64];

  { // stage sequence (int4)
    const int4* src = reinterpret_cast<const int4*>(seq + b * L_);
    int4* dst = reinterpret_cast<int4*>(stok);
    for (int i = l; i < 1024; i += 64) dst[i] = src[i];
  }
  // stage tables: kn (padded) + fused (gram, v)
  for (int idx = l * 2; idx < 4096; idx += 128) {
    float4 kv2 = *reinterpret_cast<const float4*>(&kv_table[idx]); // 2 float2
    float2 g2 = *reinterpret_cast<const float2*>(&gram[idx]);
    int row = idx >> 6, col = idx & 63;
    kn_s[row * 65 + col] = kv2.x;
    kn_s[row * 65 + col + 1] = kv2.z;
    gv_s[idx] = make_float2(g2.x, kv2.y);
    gv_s[idx + 1] = make_float2(g2.y, kv2.w);
  }
  __syncthreads();

  const int tq = stok[L_ - 1];
  qs[l] = q_table[tq * 64 + l];
  __syncthreads();

  // a_l = kn_vocab[l] . q
  float a = 0.f;
  #pragma unroll 8
  for (int i = 0; i < 64; ++i) a = fmaf(kn_s[l * 65 + i], qs[i], a);
  float r = 0.f;

  // 3 singles: t = 4094, 4093, 4092 (plain C; compiler-managed waits)
  const float2* gvl = gv_s + l;
  #pragma unroll
  for (int t = 4094; t >= 4092; --t) {
    int s0 = __builtin_amdgcn_readfirstlane(stok[t]);
    float2 g = gvl[s0 * 64];
    float c0 = readlane_f(a, s0);
    a = fmaf(-c0, g.x, a);
    r = fmaf(c0, g.y, r);
  }

  // ---- asm software pipeline over 1023 chunks of 4 steps ----
  unsigned tok_base = (unsigned)(size_t)stok;
  unsigned gv_base  = (unsigned)(size_t)gv_s + (unsigned)l * 8u;
  i32x4 tk0, tk1, tk2, tk3;
  f32x2 rb00, rb01, rb02, rb03, rb10, rb11, rb12, rb13,
        rb20, rb21, rb22, rb23, rb30, rb31, rb32, rb33;
  int ss00, ss01, ss02, ss03, ss10, ss11, ss12, ss13,
      ss20, ss21, ss22, ss23, ss30, ss31, ss32, ss33;

  // prologue, interleaved to match steady-state DS-queue pattern:
  // [T0 T1 | wait(0) | P0 T2 P1 T3]   (chunk c tokens at stok[4088-4c])
  DS128(tk0, tok_base + 16352u);   // chunk 0
  DS128(tk1, tok_base + 16336u);   // chunk 1
  LGKM(0);
  PREP(0);
  DS128(tk2, tok_base + 16320u);   // chunk 2
  PREP(1);
  DS128(tk3, tok_base + 16304u);   // chunk 3
  unsigned atok = tok_base + 16288u;  // phase p reads chunk p+4 at 16288-16p

  #pragma unroll 1
  for (int it = 0; it < 255; ++it) {   // phases 0..1019
    PHASE(0, 2);
    PHASE(1, 3);
    PHASE(2, 0);
    PHASE(3, 1);
  }
  PHASE(0, 2);   // phase 1020
  PHASE(1, 3);   // phase 1021
  PHASE(2, 0);   // phase 1022  (chunks 0..1022 all executed; 3+1023*4 = 4095)
  LGKM(0);       // drain stray prefetches before tail

  // tail: out = (r @ Wr + br) @ Wo + bo
  sh_r[l] = r;
  __syncthreads();
  float rr = br[l];
  #pragma unroll 8
  for (int i = 0; i < 64; ++i) rr = fmaf(sh_r[i], Wr[i * 64 + l], rr);
  sh_rr[l] = rr;
  __syncthreads();
  float o = bo[l];
  #pragma unroll 8
  for (int j = 0; j < 64; ++j) o = fmaf(sh_rr[j], Wo[j * 64 + l], o);
  out[b * V_ + l] = o;
}

extern "C" void kernel_launch(void* const* d_in, const int* in_sizes, int n_in,
                              void* d_out, int out_size, void* d_ws, size_t ws_size,
                              hipStream_t stream) {
  const int*   seq   = (const int*)  d_in[0];
  const float* embed = (const float*)d_in[1];
  const float* W1    = (const float*)d_in[2];
  const float* b1    = (const float*)d_in[3];
  const float* W2    = (const float*)d_in[4];
  const float* b2    = (const float*)d_in[5];
  const float* gamma = (const float*)d_in[6];
  const float* beta  = (const float*)d_in[7];
  const float* Wk    = (const float*)d_in[8];
  const float* Wv    = (const float*)d_in[9];
  const float* Wq    = (const float*)d_in[10];
  const float* Wr    = (const float*)d_in[11];
  const float* br    = (const float*)d_in[12];
  const float* Wo    = (const float*)d_in[13];
  const float* bo    = (const float*)d_in[14];
  float* out = (float*)d_out;

  float2* kv_table = (float2*)d_ws;                     // 32 KB
  float*  q_table  = (float*)((char*)d_ws + 32 * 1024); // 16 KB
  float*  gram     = (float*)((char*)d_ws + 48 * 1024); // 16 KB

  build_tables<<<V_, 64, 0, stream>>>(embed, W1, b1, W2, b2, gamma, beta,
                                      Wk, Wv, Wq, kv_table, q_table);
  build_gram<<<V_, 64, 0, stream>>>(kv_table, gram);
  scan_kernel<<<B_, 64, 0, stream>>>(seq, kv_table, q_table, gram,
                                     Wr, br, Wo, bo, out);
}